// Round 1
// baseline (23.928 us; speedup 1.0000x reference)
//
#include <hip/hip_runtime.h>

// PARAFAC forward: out[a*200+b] = sum_k F3[a,k]*F4[b,k]*F0[i0,k]*F1[i1,k]*F2[i2,k]
// K=256, dA=dB=200, fp32 everywhere. Tiny (20 MFLOP) -> latency-bound.

#define KDIM 256
#define DA 200
#define DB 200

__global__ __launch_bounds__(256) void parafac_kernel(
    const float* __restrict__ F0, const float* __restrict__ F1,
    const float* __restrict__ F2, const float* __restrict__ F3,
    const float* __restrict__ F4, const int* __restrict__ idx,
    float* __restrict__ out)
{
    const int a    = blockIdx.x;          // 0..199
    const int lane = threadIdx.x & 63;    // wave64
    const int wave = threadIdx.x >> 6;    // 0..3

    const int i0 = idx[0];
    const int i1 = idx[1];
    const int i2 = idx[2];

    const int kbase = lane * 4;           // lane owns k = 4*lane .. 4*lane+3

    const float4 p0 = *(const float4*)(F0 + (size_t)i0 * KDIM + kbase);
    const float4 p1 = *(const float4*)(F1 + (size_t)i1 * KDIM + kbase);
    const float4 p2 = *(const float4*)(F2 + (size_t)i2 * KDIM + kbase);
    const float4 f3 = *(const float4*)(F3 + (size_t)a  * KDIM + kbase);

    // s = F3[a,:] * prod, kept in registers (lane-sliced)
    const float sx = f3.x * p0.x * p1.x * p2.x;
    const float sy = f3.y * p0.y * p1.y * p2.y;
    const float sz = f3.z * p0.z * p1.z * p2.z;
    const float sw = f3.w * p0.w * p1.w * p2.w;

    // each wave handles b = wave, wave+4, ... (50 outputs per wave)
    #pragma unroll 2
    for (int b = wave; b < DB; b += 4) {
        const float4 v = *(const float4*)(F4 + (size_t)b * KDIM + kbase);
        float acc = v.x * sx + v.y * sy + v.z * sz + v.w * sw;
        // 64-lane butterfly reduction
        #pragma unroll
        for (int off = 32; off > 0; off >>= 1)
            acc += __shfl_xor(acc, off, 64);
        if (lane == 0) out[a * DB + b] = acc;
    }
}

extern "C" void kernel_launch(void* const* d_in, const int* in_sizes, int n_in,
                              void* d_out, int out_size, void* d_ws, size_t ws_size,
                              hipStream_t stream) {
    const float* F0  = (const float*)d_in[0];
    const float* F1  = (const float*)d_in[1];
    const float* F2  = (const float*)d_in[2];
    const float* F3  = (const float*)d_in[3];
    const float* F4  = (const float*)d_in[4];
    const int*   idx = (const int*)d_in[5];
    float* out = (float*)d_out;

    parafac_kernel<<<dim3(DA), dim3(256), 0, stream>>>(F0, F1, F2, F3, F4, idx, out);
}

// Round 2
// 17.395 us; speedup vs baseline: 1.3756x; 1.3756x over previous
//
#include <hip/hip_runtime.h>

// PARAFAC forward: out[a*200+b] = sum_k F3[a,k]*F4[b,k]*F0[i0,k]*F1[i1,k]*F2[i2,k]
// K=256, dA=dB=200 -> 40,000 fp32 outputs, ~20 MFLOP. Latency-bound, tiny.
//
// Round 2 structure: one 16-lane group per output element.
//   lane q (0..15) owns k = 16q .. 16q+15  (4x float4 per row)
//   4-step __shfl_xor reduction within the 16-lane group.
// Grid = 40000/16 = 2500 blocks x 256 threads = 10,000 waves (~39/CU):
// full TLP to hide L2 latency, vs round-1's 800 waves (1/SIMD).

#define KDIM 256
#define DA 200
#define DB 200

__global__ __launch_bounds__(256) void parafac_kernel(
    const float* __restrict__ F0, const float* __restrict__ F1,
    const float* __restrict__ F2, const float* __restrict__ F3,
    const float* __restrict__ F4, const int* __restrict__ idx,
    float* __restrict__ out)
{
    const int tid = threadIdx.x;
    const int g   = tid >> 4;          // group within block, 0..15
    const int q   = tid & 15;          // lane within group
    const int o   = blockIdx.x * 16 + g;   // output index, 0..39999
    const int a   = o / DB;
    const int b   = o - a * DB;

    const int i0 = idx[0];
    const int i1 = idx[1];
    const int i2 = idx[2];

    const int kb = q * 16;             // this lane's k-slice: 16 floats

    const float4* P0 = (const float4*)(F0 + (size_t)i0 * KDIM + kb);
    const float4* P1 = (const float4*)(F1 + (size_t)i1 * KDIM + kb);
    const float4* P2 = (const float4*)(F2 + (size_t)i2 * KDIM + kb);
    const float4* P3 = (const float4*)(F3 + (size_t)a  * KDIM + kb);
    const float4* P4 = (const float4*)(F4 + (size_t)b  * KDIM + kb);

    float acc = 0.0f;
    #pragma unroll
    for (int j = 0; j < 4; ++j) {
        const float4 x0 = P0[j];
        const float4 x1 = P1[j];
        const float4 x2 = P2[j];
        const float4 x3 = P3[j];
        const float4 x4 = P4[j];
        acc += x0.x * x1.x * x2.x * x3.x * x4.x;
        acc += x0.y * x1.y * x2.y * x3.y * x4.y;
        acc += x0.z * x1.z * x2.z * x3.z * x4.z;
        acc += x0.w * x1.w * x2.w * x3.w * x4.w;
    }

    // reduce over the 16 lanes of the group (xor keeps it inside the group)
    #pragma unroll
    for (int off = 1; off < 16; off <<= 1)
        acc += __shfl_xor(acc, off, 64);

    if (q == 0) out[o] = acc;
}

extern "C" void kernel_launch(void* const* d_in, const int* in_sizes, int n_in,
                              void* d_out, int out_size, void* d_ws, size_t ws_size,
                              hipStream_t stream) {
    const float* F0  = (const float*)d_in[0];
    const float* F1  = (const float*)d_in[1];
    const float* F2  = (const float*)d_in[2];
    const float* F3  = (const float*)d_in[3];
    const float* F4  = (const float*)d_in[4];
    const int*   idx = (const int*)d_in[5];
    float* out = (float*)d_out;

    const int nout   = DA * DB;                 // 40000
    const int blocks = nout / 16;               // 2500
    parafac_kernel<<<dim3(blocks), dim3(256), 0, stream>>>(F0, F1, F2, F3, F4, idx, out);
}

// Round 3
// 12.347 us; speedup vs baseline: 1.9379x; 1.4088x over previous
//
#include <hip/hip_runtime.h>

// PARAFAC forward: out[a*200+b] = sum_k F3[a,k]*F4[b,k]*F0[i0,k]*F1[i1,k]*F2[i2,k]
// K=256, dA=dB=200 -> 40,000 fp32 outputs, ~20 MFLOP. Latency/launch-bound.
//
// Round 3: one 16-lane group per (a, 4 consecutive b).
//   - s[k] = F0*F1*F2*F3[a] computed ONCE per group (amortized over 4 outputs)
//   - per b: 4x float4 F4 loads + 16 FMA + 4-step __shfl_xor reduce
//   - lane 0 stores a float4 (4 consecutive outputs, coalesced)
// Grid: 200 a * 50 chunks = 10,000 groups / 16 = 625 blocks x 256 thr = 2500 waves.

#define KDIM 256
#define DA 200
#define DB 200

__global__ __launch_bounds__(256) void parafac_kernel(
    const float* __restrict__ F0, const float* __restrict__ F1,
    const float* __restrict__ F2, const float* __restrict__ F3,
    const float* __restrict__ F4, const int* __restrict__ idx,
    float* __restrict__ out)
{
    const int tid = threadIdx.x;
    const int gg  = blockIdx.x * 16 + (tid >> 4);  // group id, 0..9999
    const int q   = tid & 15;                      // lane within group

    const int a     = gg / 50;        // 0..199
    const int chunk = gg - a * 50;    // 0..49
    const int b0    = chunk * 4;      // first of 4 consecutive b

    const int i0 = idx[0];
    const int i1 = idx[1];
    const int i2 = idx[2];

    const int kb = q * 16;            // this lane's k-slice: 16 floats

    const float4* P0 = (const float4*)(F0 + (size_t)i0 * KDIM + kb);
    const float4* P1 = (const float4*)(F1 + (size_t)i1 * KDIM + kb);
    const float4* P2 = (const float4*)(F2 + (size_t)i2 * KDIM + kb);
    const float4* P3 = (const float4*)(F3 + (size_t)a  * KDIM + kb);

    // s = F0*F1*F2*F3[a] on this lane's 16-element k-slice (once per group)
    float4 s[4];
    #pragma unroll
    for (int j = 0; j < 4; ++j) {
        const float4 x0 = P0[j];
        const float4 x1 = P1[j];
        const float4 x2 = P2[j];
        const float4 x3 = P3[j];
        s[j].x = x0.x * x1.x * x2.x * x3.x;
        s[j].y = x0.y * x1.y * x2.y * x3.y;
        s[j].z = x0.z * x1.z * x2.z * x3.z;
        s[j].w = x0.w * x1.w * x2.w * x3.w;
    }

    // 4 dot-products against F4 rows b0..b0+3 (independent chains -> ILP)
    float acc[4];
    #pragma unroll
    for (int jb = 0; jb < 4; ++jb) {
        const float4* P4 = (const float4*)(F4 + (size_t)(b0 + jb) * KDIM + kb);
        float a0 = 0.f, a1 = 0.f, a2 = 0.f, a3 = 0.f;
        #pragma unroll
        for (int j = 0; j < 4; ++j) {
            const float4 v = P4[j];
            a0 = fmaf(v.x, s[j].x, a0);
            a1 = fmaf(v.y, s[j].y, a1);
            a2 = fmaf(v.z, s[j].z, a2);
            a3 = fmaf(v.w, s[j].w, a3);
        }
        acc[jb] = (a0 + a1) + (a2 + a3);
    }

    // reduce each acc over the 16 lanes of the group
    #pragma unroll
    for (int jb = 0; jb < 4; ++jb) {
        #pragma unroll
        for (int off = 1; off < 16; off <<= 1)
            acc[jb] += __shfl_xor(acc[jb], off, 64);
    }

    if (q == 0) {
        float4 r = make_float4(acc[0], acc[1], acc[2], acc[3]);
        *(float4*)(out + (size_t)a * DB + b0) = r;   // 16B-aligned: 200a+4*chunk
    }
}

extern "C" void kernel_launch(void* const* d_in, const int* in_sizes, int n_in,
                              void* d_out, int out_size, void* d_ws, size_t ws_size,
                              hipStream_t stream) {
    const float* F0  = (const float*)d_in[0];
    const float* F1  = (const float*)d_in[1];
    const float* F2  = (const float*)d_in[2];
    const float* F3  = (const float*)d_in[3];
    const float* F4  = (const float*)d_in[4];
    const int*   idx = (const int*)d_in[5];
    float* out = (float*)d_out;

    const int groups = DA * (DB / 4);           // 10000
    const int blocks = groups / 16;             // 625
    parafac_kernel<<<dim3(blocks), dim3(256), 0, stream>>>(F0, F1, F2, F3, F4, idx, out);
}